// Round 12
// baseline (42.082 us; speedup 1.0000x reference)
//
#include <hip/hip_runtime.h>
#include <math.h>

// OrthogonalButterfly: X (1024 x 8192) fp32, 20 butterfly layers, stride 2^(l%10).
// R11 = 32.7us (pk fp32). Model: per-block serial chain ~12us x only 2
// blocks/CU to overlap -> ~30us. Barrier-scope tweaks neutral because every
// wave hits every block-wide sync.
// R12: wave-autonomous. One wave (64 lanes x 16 f2 regs) = 1024 rows x 1
// f2-col = a full column. Each wave owns its column + a private 8KB LDS slice;
// all 4 ownership transposes are wave-private (no __syncthreads; same-wave DS
// ops are in-order, lgkmcnt only). Coalesced global access preserved by
// staging through LDS at entry/exit: 2 barriers total (was 7). 16-20
// independent wave-chains per CU instead of 2-5 block convoys.
// Block 256 thr (4 waves, 4 f2-cols), LDS 32KB, grid 1024 (~5 resident/CU).
// Table byte-identical to R6-R11 (owner index = lane). pk rotations (R11).
// Swizzle sg(r) = r ^ ((r>>4)&15): 4 lanes/bank-pair (b64 floor) on all 5
// row maps and both staging patterns (hand-verified).
//
// Row maps (owner o in [0,64), element i in [0,16)):
//   P1: r = o<<4 | i                          layers s=1,2,4,8     (SL=1,2,4,8)
//   P2: r = (o&15) | i<<4 | (o>>4)<<8         layers s=16..128     (SL=1,2,4,8)
//   P3: r = (i&3) | o<<2 | (i>>2)<<8          layers s=256,512,1,2 (SL=4,8,1,2)
//   P4: r = (o&3) | (i&3)<<2 | ((i>>2)&3)<<4 | (o>>2)<<6
//                                             layers s=4..32       (SL=1,2,4,8)
//   P5: r = o | (i&3)<<6 | (i>>2)<<8          layers s=64..512     (SL=1,2,4,8)

#define NROW   1024
#define BATCH  8192
#define BATCH2 (BATCH / 2)
#define DEPTH  20
#define NANG   512
#define TAB_ELEMS (DEPTH * NANG)
#define TAB_BYTES ((size_t)TAB_ELEMS * 8)

typedef float v2f __attribute__((ext_vector_type(2)));

__device__ __host__ __forceinline__ int rowP1(int o, int i){ return (o<<4)|i; }
__device__ __host__ __forceinline__ int rowP2(int o, int i){ return (o&15) | (i<<4) | ((o>>4)<<8); }
__device__ __host__ __forceinline__ int rowP3(int o, int i){ return (i&3) | (o<<2) | ((i>>2)<<8); }
__device__ __host__ __forceinline__ int rowP4(int o, int i){ return (o&3) | ((i&3)<<2) | (((i>>2)&3)<<4) | ((o>>2)<<6); }
__device__ __host__ __forceinline__ int rowP5(int o, int i){ return o | ((i&3)<<6) | ((i>>2)<<8); }

// ---------------- angle table build (identical to R6-R11, verified) ----------------
__global__ void build_tab_kernel(const float* __restrict__ ang,
                                 float2* __restrict__ tab) {
    int idx = blockIdx.x * blockDim.x + threadIdx.x;
    if (idx >= TAB_ELEMS) return;
    int l = idx >> 9;
    int slot = idx & (NANG - 1);
    int sub = slot >> 3, p = slot & 7;
    int sp = l % 10;
    int SL, ph;
    if (l < 4)       { ph = 0; SL = 1 << l; }
    else if (l < 8)  { ph = 1; SL = 1 << (l - 4); }
    else if (l < 12) { ph = 2; SL = (l == 8) ? 4 : (l == 9) ? 8 : (l == 10) ? 1 : 2; }
    else if (l < 16) { ph = 3; SL = 1 << (l - 12); }
    else             { ph = 4; SL = 1 << (l - 16); }
    int i0 = 2 * (p / SL) * SL + p % SL;
    int r;
    if (ph == 0)      r = rowP1(sub, i0);
    else if (ph == 1) r = rowP2(sub, i0);
    else if (ph == 2) r = rowP3(sub, i0);
    else if (ph == 3) r = rowP4(sub, i0);
    else              r = rowP5(sub, i0);
    int s = 1 << sp;
    int a = ((r >> (sp + 1)) << sp) | (r & (s - 1));
    float th = ang[l * NANG + a];
    float sv, cv;
    sincosf(th, &sv, &cv);
    tab[idx] = make_float2(cv, sv);
}

// ---------------- main kernel ----------------
__device__ __forceinline__ void rotp(v2f& a, v2f& b, float cv, float sv) {
    v2f c = {cv, cv}, s = {sv, sv};
    v2f x0 = a, x1 = b;
    a = __builtin_elementwise_fma(c, x0, s * x1);
    b = __builtin_elementwise_fma(-s, x0, c * x1);
}

// One layer on 16 v2f rows, local pair-stride SL. Table slice = 4 float4 at
// tl + 8*o (8 cos/sin pairs for this owner).
template<int SL>
__device__ __forceinline__ void layer_tab(v2f y[16],
                                          const float2* __restrict__ tl,
                                          int o) {
    const float4* q4 = reinterpret_cast<const float4*>(tl + 8 * o);
    #pragma unroll
    for (int v = 0; v < 4; ++v) {
        float4 q = q4[v];
        int p0 = 2 * v, p1 = 2 * v + 1;
        int a0 = 2 * (p0 / SL) * SL + p0 % SL;   // constant-folds
        int a1 = 2 * (p1 / SL) * SL + p1 % SL;
        rotp(y[a0], y[a0 + SL], q.x, q.y);
        rotp(y[a1], y[a1 + SL], q.z, q.w);
    }
}

// Fallback without workspace: inline sincos.
template<int SL, int PH, int SP>
__device__ __forceinline__ void layer_notab(v2f y[16],
                                            const float* __restrict__ angL,
                                            int o) {
    #pragma unroll
    for (int p = 0; p < 8; ++p) {
        int i0 = 2 * (p / SL) * SL + p % SL;
        int r;
        if (PH == 0)      r = rowP1(o, i0);
        else if (PH == 1) r = rowP2(o, i0);
        else if (PH == 2) r = rowP3(o, i0);
        else if (PH == 3) r = rowP4(o, i0);
        else              r = rowP5(o, i0);
        int a = ((r >> (SP + 1)) << SP) | (r & ((1 << SP) - 1));
        float th = angL[a];
        float sv, cv;
        __sincosf(th, &sv, &cv);
        rotp(y[i0], y[i0 + SL], cv, sv);
    }
}

// Swizzle within a 1024-f2 column slice: bank-pair = sg(r)&15.
__device__ __forceinline__ int sg(int r) { return r ^ ((r >> 4) & 15); }

template<bool USE_TAB>
__global__ __launch_bounds__(256) void butterfly_kernel(
        const float* __restrict__ X, const float* __restrict__ ang,
        const float2* __restrict__ tab, float* __restrict__ out) {
    __shared__ v2f lds[4 * 1024];        // 32 KB: 4 column slices of 8 KB
    int t = threadIdx.x;
    int c = t & 3;                       // staging: f2-col within block
    int sub = t >> 2;                    // staging: [0,64)
    int w = t >> 6;                      // compute: wave id = owned column
    int ln = t & 63;                     // compute: lane = owner index
    int bid = blockIdx.x;
    int L = ((bid & 7) << 7) | (bid >> 3);   // XCD-aware, bijective (1024 = 8*128)
    int col2 = L << 2;                   // block's base f2-col

    // ---- stage in: coalesced load (32B segments, R10-proven), park in LDS ----
    {
        const v2f* Xp = reinterpret_cast<const v2f*>(X) + col2 + c;
        #pragma unroll
        for (int i = 0; i < 16; ++i) {
            v2f v = Xp[rowP1(sub, i) * BATCH2];
            lds[(c << 10) | sg(rowP1(sub, i))] = v;
        }
    }
    __syncthreads();                     // barrier 1 of 2

    v2f* slice = lds + (w << 10);        // this wave's private column slice
    v2f y[16];
    #pragma unroll
    for (int i = 0; i < 16; ++i) y[i] = slice[sg(rowP1(ln, i))];

    if (USE_TAB) {
        layer_tab<1>(y, tab + 0 * NANG, ln);     // s=1
        layer_tab<2>(y, tab + 1 * NANG, ln);     // s=2
        layer_tab<4>(y, tab + 2 * NANG, ln);     // s=4
        layer_tab<8>(y, tab + 3 * NANG, ln);     // s=8
    } else {
        layer_notab<1,0,0>(y, ang + 0 * NANG, ln);
        layer_notab<2,0,1>(y, ang + 1 * NANG, ln);
        layer_notab<4,0,2>(y, ang + 2 * NANG, ln);
        layer_notab<8,0,3>(y, ang + 3 * NANG, ln);
    }
    // T1 (wave-private): wr P1 / rd P2
    __builtin_amdgcn_wave_barrier();
    #pragma unroll
    for (int i = 0; i < 16; ++i) slice[sg(rowP1(ln, i))] = y[i];
    __builtin_amdgcn_wave_barrier();
    #pragma unroll
    for (int i = 0; i < 16; ++i) y[i] = slice[sg(rowP2(ln, i))];

    if (USE_TAB) {
        layer_tab<1>(y, tab + 4 * NANG, ln);     // s=16
        layer_tab<2>(y, tab + 5 * NANG, ln);     // s=32
        layer_tab<4>(y, tab + 6 * NANG, ln);     // s=64
        layer_tab<8>(y, tab + 7 * NANG, ln);     // s=128
    } else {
        layer_notab<1,1,4>(y, ang + 4 * NANG, ln);
        layer_notab<2,1,5>(y, ang + 5 * NANG, ln);
        layer_notab<4,1,6>(y, ang + 6 * NANG, ln);
        layer_notab<8,1,7>(y, ang + 7 * NANG, ln);
    }
    // T2: wr P2 / rd P3
    __builtin_amdgcn_wave_barrier();
    #pragma unroll
    for (int i = 0; i < 16; ++i) slice[sg(rowP2(ln, i))] = y[i];
    __builtin_amdgcn_wave_barrier();
    #pragma unroll
    for (int i = 0; i < 16; ++i) y[i] = slice[sg(rowP3(ln, i))];

    if (USE_TAB) {
        layer_tab<4>(y, tab +  8 * NANG, ln);    // s=256
        layer_tab<8>(y, tab +  9 * NANG, ln);    // s=512
        layer_tab<1>(y, tab + 10 * NANG, ln);    // s=1
        layer_tab<2>(y, tab + 11 * NANG, ln);    // s=2
    } else {
        layer_notab<4,2,8>(y, ang +  8 * NANG, ln);
        layer_notab<8,2,9>(y, ang +  9 * NANG, ln);
        layer_notab<1,2,0>(y, ang + 10 * NANG, ln);
        layer_notab<2,2,1>(y, ang + 11 * NANG, ln);
    }
    // T3: wr P3 / rd P4
    __builtin_amdgcn_wave_barrier();
    #pragma unroll
    for (int i = 0; i < 16; ++i) slice[sg(rowP3(ln, i))] = y[i];
    __builtin_amdgcn_wave_barrier();
    #pragma unroll
    for (int i = 0; i < 16; ++i) y[i] = slice[sg(rowP4(ln, i))];

    if (USE_TAB) {
        layer_tab<1>(y, tab + 12 * NANG, ln);    // s=4
        layer_tab<2>(y, tab + 13 * NANG, ln);    // s=8
        layer_tab<4>(y, tab + 14 * NANG, ln);    // s=16
        layer_tab<8>(y, tab + 15 * NANG, ln);    // s=32
    } else {
        layer_notab<1,3,2>(y, ang + 12 * NANG, ln);
        layer_notab<2,3,3>(y, ang + 13 * NANG, ln);
        layer_notab<4,3,4>(y, ang + 14 * NANG, ln);
        layer_notab<8,3,5>(y, ang + 15 * NANG, ln);
    }
    // T4: wr P4 / rd P5
    __builtin_amdgcn_wave_barrier();
    #pragma unroll
    for (int i = 0; i < 16; ++i) slice[sg(rowP4(ln, i))] = y[i];
    __builtin_amdgcn_wave_barrier();
    #pragma unroll
    for (int i = 0; i < 16; ++i) y[i] = slice[sg(rowP5(ln, i))];

    if (USE_TAB) {
        layer_tab<1>(y, tab + 16 * NANG, ln);    // s=64
        layer_tab<2>(y, tab + 17 * NANG, ln);    // s=128
        layer_tab<4>(y, tab + 18 * NANG, ln);    // s=256
        layer_tab<8>(y, tab + 19 * NANG, ln);    // s=512
    } else {
        layer_notab<1,4,6>(y, ang + 16 * NANG, ln);
        layer_notab<2,4,7>(y, ang + 17 * NANG, ln);
        layer_notab<4,4,8>(y, ang + 18 * NANG, ln);
        layer_notab<8,4,9>(y, ang + 19 * NANG, ln);
    }

    // ---- stage out: park in LDS, barrier, coalesced store ----
    __builtin_amdgcn_wave_barrier();
    #pragma unroll
    for (int i = 0; i < 16; ++i) slice[sg(rowP5(ln, i))] = y[i];
    __syncthreads();                     // barrier 2 of 2
    {
        v2f* Op = reinterpret_cast<v2f*>(out) + col2 + c;
        #pragma unroll
        for (int i = 0; i < 16; ++i) {
            v2f v = lds[(c << 10) | sg(rowP5(sub, i))];
            Op[rowP5(sub, i) * BATCH2] = v;
        }
    }
}

extern "C" void kernel_launch(void* const* d_in, const int* in_sizes, int n_in,
                              void* d_out, int out_size, void* d_ws, size_t ws_size,
                              hipStream_t stream) {
    (void)in_sizes; (void)n_in; (void)out_size;
    const float* X   = (const float*)d_in[0];
    const float* ang = (const float*)d_in[1];
    float* out = (float*)d_out;

    bool use_tab = (d_ws != nullptr) && (ws_size >= TAB_BYTES);
    if (use_tab) {
        float2* tab = (float2*)d_ws;
        build_tab_kernel<<<(TAB_ELEMS + 255) / 256, 256, 0, stream>>>(ang, tab);
        butterfly_kernel<true><<<1024, 256, 0, stream>>>(X, ang, tab, out);
    } else {
        butterfly_kernel<false><<<1024, 256, 0, stream>>>(X, ang, nullptr, out);
    }
}

// Round 13
// 35.169 us; speedup vs baseline: 1.1965x; 1.1965x over previous
//
#include <hip/hip_runtime.h>
#include <math.h>

// OrthogonalButterfly: X (1024 x 8192) fp32, 20 butterfly layers, stride 2^(l%10).
// R11 = 32.7us best (R8 geom + pk fp32). R12 (wave-private transposes) regressed
// but exposed the lever: VGPR 48 -> occupancy 30% vs VGPR 84-88 -> 19%
// (waves/SIMD halves above 64 VGPR). R10 geometry allows 5 blocks/CU by LDS,
// but VGPR 88 capped it at 4 waves/SIMD and ~6 resident waves.
// R13: R10 geometry (256 thr = 4 f2cols x 64 subs, 32KB LDS, grid 1024)
//      + R11 pk rotations + __launch_bounds__(256,8) -> 64-VGPR cap
//      -> 20 resident waves/CU (5 independent blocks). Everything else
//      byte-identical to R10.
//
// Phase row maps (sub in [0,64), i in [0,16)):
//   P1: r = sub<<4 | i                          layers s=1,2,4,8     (SL=1,2,4,8)
//   P2: r = (sub&15) | i<<4 | (sub>>4)<<8       layers s=16..128     (SL=1,2,4,8)
//   P3: r = (i&3) | sub<<2 | (i>>2)<<8          layers s=256,512,1,2 (SL=4,8,1,2)
//   P4: r = (sub&3) | (i&3)<<2 | ((i>>2)&3)<<4 | (sub>>2)<<6
//                                               layers s=4..32       (SL=1,2,4,8)
//   P5: r = sub | (i&3)<<6 | (i>>2)<<8          layers s=64..512     (SL=1,2,4,8)

#define NROW   1024
#define BATCH  8192
#define BATCH2 (BATCH / 2)
#define DEPTH  20
#define NANG   512
#define TAB_ELEMS (DEPTH * NANG)
#define TAB_BYTES ((size_t)TAB_ELEMS * 8)

typedef float v2f __attribute__((ext_vector_type(2)));

__device__ __host__ __forceinline__ int rowP1(int sub, int i){ return (sub<<4)|i; }
__device__ __host__ __forceinline__ int rowP2(int sub, int i){ return (sub&15) | (i<<4) | ((sub>>4)<<8); }
__device__ __host__ __forceinline__ int rowP3(int sub, int i){ return (i&3) | (sub<<2) | ((i>>2)<<8); }
__device__ __host__ __forceinline__ int rowP4(int sub, int i){ return (sub&3) | ((i&3)<<2) | (((i>>2)&3)<<4) | ((sub>>2)<<6); }
__device__ __host__ __forceinline__ int rowP5(int sub, int i){ return sub | ((i&3)<<6) | ((i>>2)<<8); }

// ---------------- angle table build (identical to R6-R12, verified) ----------------
__global__ void build_tab_kernel(const float* __restrict__ ang,
                                 float2* __restrict__ tab) {
    int idx = blockIdx.x * blockDim.x + threadIdx.x;
    if (idx >= TAB_ELEMS) return;
    int l = idx >> 9;
    int slot = idx & (NANG - 1);
    int sub = slot >> 3, p = slot & 7;
    int sp = l % 10;
    int SL, ph;
    if (l < 4)       { ph = 0; SL = 1 << l; }
    else if (l < 8)  { ph = 1; SL = 1 << (l - 4); }
    else if (l < 12) { ph = 2; SL = (l == 8) ? 4 : (l == 9) ? 8 : (l == 10) ? 1 : 2; }
    else if (l < 16) { ph = 3; SL = 1 << (l - 12); }
    else             { ph = 4; SL = 1 << (l - 16); }
    int i0 = 2 * (p / SL) * SL + p % SL;
    int r;
    if (ph == 0)      r = rowP1(sub, i0);
    else if (ph == 1) r = rowP2(sub, i0);
    else if (ph == 2) r = rowP3(sub, i0);
    else if (ph == 3) r = rowP4(sub, i0);
    else              r = rowP5(sub, i0);
    int s = 1 << sp;
    int a = ((r >> (sp + 1)) << sp) | (r & (s - 1));
    float th = ang[l * NANG + a];
    float sv, cv;
    sincosf(th, &sv, &cv);
    tab[idx] = make_float2(cv, sv);
}

// ---------------- main kernel ----------------
// Packed rotation (R11-validated): both f2 lanes share (c,s); neg folds into
// the pk_fma modifier.
__device__ __forceinline__ void rotp(v2f& a, v2f& b, float cv, float sv) {
    v2f c = {cv, cv}, s = {sv, sv};
    v2f x0 = a, x1 = b;
    a = __builtin_elementwise_fma(c, x0, s * x1);
    b = __builtin_elementwise_fma(-s, x0, c * x1);
}

// One layer on 16 v2f rows, local pair-stride SL. Table slice = 4 float4
// at tl + 8*sub (8 cos/sin pairs, shared by the 4 c-lanes -> broadcast).
template<int SL>
__device__ __forceinline__ void layer_tab(v2f y[16],
                                          const float2* __restrict__ tl,
                                          int sub) {
    const float4* q4 = reinterpret_cast<const float4*>(tl + 8 * sub);
    #pragma unroll
    for (int v = 0; v < 4; ++v) {
        float4 q = q4[v];
        int p0 = 2 * v, p1 = 2 * v + 1;
        int a0 = 2 * (p0 / SL) * SL + p0 % SL;   // constant-folds
        int a1 = 2 * (p1 / SL) * SL + p1 % SL;
        rotp(y[a0], y[a0 + SL], q.x, q.y);
        rotp(y[a1], y[a1 + SL], q.z, q.w);
    }
}

// Fallback without workspace: inline sincos (angles shared by the 2 cols).
template<int SL, int PH, int SP>
__device__ __forceinline__ void layer_notab(v2f y[16],
                                            const float* __restrict__ angL,
                                            int sub) {
    #pragma unroll
    for (int p = 0; p < 8; ++p) {
        int i0 = 2 * (p / SL) * SL + p % SL;
        int r;
        if (PH == 0)      r = rowP1(sub, i0);
        else if (PH == 1) r = rowP2(sub, i0);
        else if (PH == 2) r = rowP3(sub, i0);
        else if (PH == 3) r = rowP4(sub, i0);
        else              r = rowP5(sub, i0);
        int a = ((r >> (SP + 1)) << SP) | (r & ((1 << SP) - 1));
        float th = angL[a];
        float sv, cv;
        __sincosf(th, &sv, &cv);
        rotp(y[i0], y[i0 + SL], cv, sv);
    }
}

// LDS element address for (f2-col c, row r). sigma involution pushes sub bits
// into the bank index on all phase maps; c<<1 decorrelates columns.
__device__ __forceinline__ int eaddr(int c, int r) {
    return (c << 10) | ((r ^ ((r >> 4) & 15)) ^ (c << 1));
}

template<bool USE_TAB>
__global__ __launch_bounds__(256, 8) void butterfly_kernel(
        const float* __restrict__ X, const float* __restrict__ ang,
        const float2* __restrict__ tab, float* __restrict__ out) {
    __shared__ v2f lds2[4 * 1024];       // 32 KB -> 5 resident blocks/CU
    int t = threadIdx.x;
    int c = t & 3;                       // f2-column within block
    int sub = t >> 2;                    // [0,64)
    int bid = blockIdx.x;
    int L = ((bid & 7) << 7) | (bid >> 3);   // XCD-aware, bijective (1024 = 8*128)
    int col2 = (L << 2) + c;             // f2-col in [0,4096)

    v2f y[16];
    const v2f* Xp = reinterpret_cast<const v2f*>(X) + col2;
    #pragma unroll
    for (int i = 0; i < 16; ++i)
        y[i] = Xp[rowP1(sub, i) * BATCH2];

    if (USE_TAB) {
        layer_tab<1>(y, tab + 0 * NANG, sub);    // s=1
        layer_tab<2>(y, tab + 1 * NANG, sub);    // s=2
        layer_tab<4>(y, tab + 2 * NANG, sub);    // s=4
        layer_tab<8>(y, tab + 3 * NANG, sub);    // s=8
    } else {
        layer_notab<1,0,0>(y, ang + 0 * NANG, sub);
        layer_notab<2,0,1>(y, ang + 1 * NANG, sub);
        layer_notab<4,0,2>(y, ang + 2 * NANG, sub);
        layer_notab<8,0,3>(y, ang + 3 * NANG, sub);
    }
    // T1: wr P1 / rd P2
    #pragma unroll
    for (int i = 0; i < 16; ++i) lds2[eaddr(c, rowP1(sub, i))] = y[i];
    __syncthreads();
    #pragma unroll
    for (int i = 0; i < 16; ++i) y[i] = lds2[eaddr(c, rowP2(sub, i))];

    if (USE_TAB) {
        layer_tab<1>(y, tab + 4 * NANG, sub);    // s=16
        layer_tab<2>(y, tab + 5 * NANG, sub);    // s=32
        layer_tab<4>(y, tab + 6 * NANG, sub);    // s=64
        layer_tab<8>(y, tab + 7 * NANG, sub);    // s=128
    } else {
        layer_notab<1,1,4>(y, ang + 4 * NANG, sub);
        layer_notab<2,1,5>(y, ang + 5 * NANG, sub);
        layer_notab<4,1,6>(y, ang + 6 * NANG, sub);
        layer_notab<8,1,7>(y, ang + 7 * NANG, sub);
    }
    // T2: wr P2 / rd P3
    __syncthreads();
    #pragma unroll
    for (int i = 0; i < 16; ++i) lds2[eaddr(c, rowP2(sub, i))] = y[i];
    __syncthreads();
    #pragma unroll
    for (int i = 0; i < 16; ++i) y[i] = lds2[eaddr(c, rowP3(sub, i))];

    if (USE_TAB) {
        layer_tab<4>(y, tab +  8 * NANG, sub);   // s=256
        layer_tab<8>(y, tab +  9 * NANG, sub);   // s=512
        layer_tab<1>(y, tab + 10 * NANG, sub);   // s=1
        layer_tab<2>(y, tab + 11 * NANG, sub);   // s=2
    } else {
        layer_notab<4,2,8>(y, ang +  8 * NANG, sub);
        layer_notab<8,2,9>(y, ang +  9 * NANG, sub);
        layer_notab<1,2,0>(y, ang + 10 * NANG, sub);
        layer_notab<2,2,1>(y, ang + 11 * NANG, sub);
    }
    // T3: wr P3 / rd P4
    __syncthreads();
    #pragma unroll
    for (int i = 0; i < 16; ++i) lds2[eaddr(c, rowP3(sub, i))] = y[i];
    __syncthreads();
    #pragma unroll
    for (int i = 0; i < 16; ++i) y[i] = lds2[eaddr(c, rowP4(sub, i))];

    if (USE_TAB) {
        layer_tab<1>(y, tab + 12 * NANG, sub);   // s=4
        layer_tab<2>(y, tab + 13 * NANG, sub);   // s=8
        layer_tab<4>(y, tab + 14 * NANG, sub);   // s=16
        layer_tab<8>(y, tab + 15 * NANG, sub);   // s=32
    } else {
        layer_notab<1,3,2>(y, ang + 12 * NANG, sub);
        layer_notab<2,3,3>(y, ang + 13 * NANG, sub);
        layer_notab<4,3,4>(y, ang + 14 * NANG, sub);
        layer_notab<8,3,5>(y, ang + 15 * NANG, sub);
    }
    // T4: wr P4 / rd P5
    __syncthreads();
    #pragma unroll
    for (int i = 0; i < 16; ++i) lds2[eaddr(c, rowP4(sub, i))] = y[i];
    __syncthreads();
    #pragma unroll
    for (int i = 0; i < 16; ++i) y[i] = lds2[eaddr(c, rowP5(sub, i))];

    if (USE_TAB) {
        layer_tab<1>(y, tab + 16 * NANG, sub);   // s=64
        layer_tab<2>(y, tab + 17 * NANG, sub);   // s=128
        layer_tab<4>(y, tab + 18 * NANG, sub);   // s=256
        layer_tab<8>(y, tab + 19 * NANG, sub);   // s=512
    } else {
        layer_notab<1,4,6>(y, ang + 16 * NANG, sub);
        layer_notab<2,4,7>(y, ang + 17 * NANG, sub);
        layer_notab<4,4,8>(y, ang + 18 * NANG, sub);
        layer_notab<8,4,9>(y, ang + 19 * NANG, sub);
    }

    v2f* Op = reinterpret_cast<v2f*>(out) + col2;
    #pragma unroll
    for (int i = 0; i < 16; ++i)
        Op[rowP5(sub, i) * BATCH2] = y[i];
}

extern "C" void kernel_launch(void* const* d_in, const int* in_sizes, int n_in,
                              void* d_out, int out_size, void* d_ws, size_t ws_size,
                              hipStream_t stream) {
    (void)in_sizes; (void)n_in; (void)out_size;
    const float* X   = (const float*)d_in[0];
    const float* ang = (const float*)d_in[1];
    float* out = (float*)d_out;

    bool use_tab = (d_ws != nullptr) && (ws_size >= TAB_BYTES);
    if (use_tab) {
        float2* tab = (float2*)d_ws;
        build_tab_kernel<<<(TAB_ELEMS + 255) / 256, 256, 0, stream>>>(ang, tab);
        butterfly_kernel<true><<<1024, 256, 0, stream>>>(X, ang, tab, out);
    } else {
        butterfly_kernel<false><<<1024, 256, 0, stream>>>(X, ang, nullptr, out);
    }
}

// Round 14
// 31.663 us; speedup vs baseline: 1.3291x; 1.1107x over previous
//
#include <hip/hip_runtime.h>
#include <math.h>

// OrthogonalButterfly: X (1024 x 8192) fp32, 20 butterfly layers, stride 2^(l%10).
// R11 = 32.7us best (512thr, 8 f2-cols x 64 subs, y=f2[16], 4T/7B, pk fp32).
// R13 killed the occupancy theory (48 VGPR, 20-wave cap -> 35us). Remaining
// non-essential cost: DS ops + addressing (128 b64 + ~128 XOR) and 7 barriers.
// R14: y = v2f[32] per thread -> only TWO ownership maps:
//   A: r = sub<<5 | i   (i in [0,32))  layers s=1..16   (SL=1,2,4,8,16)
//   B: r = sub | i<<5                  layers s=32..512 (SL=1,2,4,8,16)
// Schedule A(5L) T1 B(5L) T2 A(5L) T3 B(5L): 3 transposes, 5 barriers.
// A-side LDS ops pair consecutive rows -> b128 (16 ops); B-side b64 (32) ->
// 4.5 DS-ops/elem vs 8. Block 512 thr = 16 f2-cols x 32 subs -> global
// loads/stores are full 128B lines. LDS 128KB, grid 256 = 1 block/CU.
// Swizzle xr=(c&7)<<1, elem = c<<10 | (r^xr): b128 8 lanes/quad (floor),
// b64 <=4 lanes/bank-pair (~free); bit0 untouched keeps b128 alignment.

#define NROW   1024
#define BATCH  8192
#define BATCH2 (BATCH / 2)
#define DEPTH  20
#define NANG   512
#define TAB_ELEMS (DEPTH * NANG)
#define TAB_BYTES ((size_t)TAB_ELEMS * 8)

typedef float v2f __attribute__((ext_vector_type(2)));

__device__ __host__ __forceinline__ int rowA(int sub, int i){ return (sub << 5) | i; }
__device__ __host__ __forceinline__ int rowB(int sub, int i){ return sub | (i << 5); }

// ---------------- angle table build ----------------
// slot = 16*sub + p (sub in [0,32), p in [0,16)). Layer l: m10 = l%10,
// SL = 2^(m10%5), phase B iff m10>=5, sp = m10. Pair p -> i0 = 2*(p/SL)*SL
// + p%SL -> r (row map) -> original angle a = ((r>>(sp+1))<<sp) | (r&(2^sp-1)).
__global__ void build_tab_kernel(const float* __restrict__ ang,
                                 float2* __restrict__ tab) {
    int idx = blockIdx.x * blockDim.x + threadIdx.x;
    if (idx >= TAB_ELEMS) return;
    int l = idx >> 9;
    int slot = idx & (NANG - 1);
    int sub = slot >> 4, p = slot & 15;
    int m10 = l % 10;
    int sp = m10;
    int SL = 1 << (m10 % 5);
    int i0 = 2 * (p / SL) * SL + p % SL;
    int r = (m10 >= 5) ? rowB(sub, i0) : rowA(sub, i0);
    int a = ((r >> (sp + 1)) << sp) | (r & ((1 << sp) - 1));
    float th = ang[l * NANG + a];
    float sv, cv;
    sincosf(th, &sv, &cv);
    tab[idx] = make_float2(cv, sv);
}

// ---------------- main kernel ----------------
// Packed rotation (R11-validated): both f2 lanes share (c,s).
__device__ __forceinline__ void rotp(v2f& a, v2f& b, float cv, float sv) {
    v2f c = {cv, cv}, s = {sv, sv};
    v2f x0 = a, x1 = b;
    a = __builtin_elementwise_fma(c, x0, s * x1);
    b = __builtin_elementwise_fma(-s, x0, c * x1);
}

// One layer on 32 v2f rows, local pair-stride SL. Table slice = 8 float4 at
// tf4 + l*256 + 8*sub (16 cos/sin pairs, shared by 16 c-lanes -> broadcast).
template<int SL>
__device__ __forceinline__ void layer_tab(v2f y[32],
                                          const float4* __restrict__ q4) {
    #pragma unroll
    for (int v = 0; v < 8; ++v) {
        float4 q = q4[v];
        int p0 = 2 * v, p1 = 2 * v + 1;
        int a0 = 2 * (p0 / SL) * SL + p0 % SL;   // constant-folds
        int a1 = 2 * (p1 / SL) * SL + p1 % SL;
        rotp(y[a0], y[a0 + SL], q.x, q.y);
        rotp(y[a1], y[a1 + SL], q.z, q.w);
    }
}

// Fallback without workspace: inline sincos.
template<int SL, bool PB, int SP>
__device__ __forceinline__ void layer_notab(v2f y[32],
                                            const float* __restrict__ angL,
                                            int sub) {
    #pragma unroll
    for (int p = 0; p < 16; ++p) {
        int i0 = 2 * (p / SL) * SL + p % SL;
        int r = PB ? rowB(sub, i0) : rowA(sub, i0);
        int a = ((r >> (SP + 1)) << SP) | (r & ((1 << SP) - 1));
        float th = angL[a];
        float sv, cv;
        __sincosf(th, &sv, &cv);
        rotp(y[i0], y[i0 + SL], cv, sv);
    }
}

template<bool USE_TAB>
__global__ __launch_bounds__(512) void butterfly_kernel(
        const float* __restrict__ X, const float* __restrict__ ang,
        const float2* __restrict__ tab, float* __restrict__ out) {
    __shared__ v2f lds[16 * 1024];       // 128 KB -> 1 block/CU
    int t = threadIdx.x;
    int c = t & 15;                      // f2-column within block
    int sub = t >> 4;                    // [0,32)
    int bid = blockIdx.x;
    int L = ((bid & 7) << 5) | (bid >> 3);   // XCD-aware, bijective (256 = 8*32)
    int col2 = (L << 4) + c;             // f2-col in [0,4096)
    int xr = (c & 7) << 1;               // swizzle (bit0 clear -> b128 ok)
    v2f* base = lds + (c << 10);

    v2f y[32];
    const v2f* Xp = reinterpret_cast<const v2f*>(X) + col2;
    #pragma unroll
    for (int i = 0; i < 32; ++i)
        y[i] = Xp[rowA(sub, i) * BATCH2];        // 128B-line coalesced

    const float4* tf4 = reinterpret_cast<const float4*>(tab);
    if (USE_TAB) {
        layer_tab<1 >(y, tf4 + 0 * 256 + 8 * sub);   // s=1
        layer_tab<2 >(y, tf4 + 1 * 256 + 8 * sub);   // s=2
        layer_tab<4 >(y, tf4 + 2 * 256 + 8 * sub);   // s=4
        layer_tab<8 >(y, tf4 + 3 * 256 + 8 * sub);   // s=8
        layer_tab<16>(y, tf4 + 4 * 256 + 8 * sub);   // s=16
    } else {
        layer_notab<1 ,false,0>(y, ang + 0 * NANG, sub);
        layer_notab<2 ,false,1>(y, ang + 1 * NANG, sub);
        layer_notab<4 ,false,2>(y, ang + 2 * NANG, sub);
        layer_notab<8 ,false,3>(y, ang + 3 * NANG, sub);
        layer_notab<16,false,4>(y, ang + 4 * NANG, sub);
    }
    // T1: wr A (b128) / rd B (b64)
    #pragma unroll
    for (int u = 0; u < 16; ++u)
        *reinterpret_cast<float4*>(&base[((sub << 5) + 2 * u) ^ xr]) =
            make_float4(y[2*u].x, y[2*u].y, y[2*u+1].x, y[2*u+1].y);
    __syncthreads();
    #pragma unroll
    for (int i = 0; i < 32; ++i) y[i] = base[rowB(sub, i) ^ xr];

    if (USE_TAB) {
        layer_tab<1 >(y, tf4 + 5 * 256 + 8 * sub);   // s=32
        layer_tab<2 >(y, tf4 + 6 * 256 + 8 * sub);   // s=64
        layer_tab<4 >(y, tf4 + 7 * 256 + 8 * sub);   // s=128
        layer_tab<8 >(y, tf4 + 8 * 256 + 8 * sub);   // s=256
        layer_tab<16>(y, tf4 + 9 * 256 + 8 * sub);   // s=512
    } else {
        layer_notab<1 ,true,5>(y, ang + 5 * NANG, sub);
        layer_notab<2 ,true,6>(y, ang + 6 * NANG, sub);
        layer_notab<4 ,true,7>(y, ang + 7 * NANG, sub);
        layer_notab<8 ,true,8>(y, ang + 8 * NANG, sub);
        layer_notab<16,true,9>(y, ang + 9 * NANG, sub);
    }
    // T2: wr B (b64) / rd A (b128)
    __syncthreads();
    #pragma unroll
    for (int i = 0; i < 32; ++i) base[rowB(sub, i) ^ xr] = y[i];
    __syncthreads();
    #pragma unroll
    for (int u = 0; u < 16; ++u) {
        float4 v = *reinterpret_cast<const float4*>(&base[((sub << 5) + 2 * u) ^ xr]);
        y[2*u].x = v.x; y[2*u].y = v.y; y[2*u+1].x = v.z; y[2*u+1].y = v.w;
    }

    if (USE_TAB) {
        layer_tab<1 >(y, tf4 + 10 * 256 + 8 * sub);  // s=1
        layer_tab<2 >(y, tf4 + 11 * 256 + 8 * sub);  // s=2
        layer_tab<4 >(y, tf4 + 12 * 256 + 8 * sub);  // s=4
        layer_tab<8 >(y, tf4 + 13 * 256 + 8 * sub);  // s=8
        layer_tab<16>(y, tf4 + 14 * 256 + 8 * sub);  // s=16
    } else {
        layer_notab<1 ,false,0>(y, ang + 10 * NANG, sub);
        layer_notab<2 ,false,1>(y, ang + 11 * NANG, sub);
        layer_notab<4 ,false,2>(y, ang + 12 * NANG, sub);
        layer_notab<8 ,false,3>(y, ang + 13 * NANG, sub);
        layer_notab<16,false,4>(y, ang + 14 * NANG, sub);
    }
    // T3: wr A (b128) / rd B (b64)
    __syncthreads();
    #pragma unroll
    for (int u = 0; u < 16; ++u)
        *reinterpret_cast<float4*>(&base[((sub << 5) + 2 * u) ^ xr]) =
            make_float4(y[2*u].x, y[2*u].y, y[2*u+1].x, y[2*u+1].y);
    __syncthreads();
    #pragma unroll
    for (int i = 0; i < 32; ++i) y[i] = base[rowB(sub, i) ^ xr];

    if (USE_TAB) {
        layer_tab<1 >(y, tf4 + 15 * 256 + 8 * sub);  // s=32
        layer_tab<2 >(y, tf4 + 16 * 256 + 8 * sub);  // s=64
        layer_tab<4 >(y, tf4 + 17 * 256 + 8 * sub);  // s=128
        layer_tab<8 >(y, tf4 + 18 * 256 + 8 * sub);  // s=256
        layer_tab<16>(y, tf4 + 19 * 256 + 8 * sub);  // s=512
    } else {
        layer_notab<1 ,true,5>(y, ang + 15 * NANG, sub);
        layer_notab<2 ,true,6>(y, ang + 16 * NANG, sub);
        layer_notab<4 ,true,7>(y, ang + 17 * NANG, sub);
        layer_notab<8 ,true,8>(y, ang + 18 * NANG, sub);
        layer_notab<16,true,9>(y, ang + 19 * NANG, sub);
    }

    v2f* Op = reinterpret_cast<v2f*>(out) + col2;
    #pragma unroll
    for (int i = 0; i < 32; ++i)
        Op[rowB(sub, i) * BATCH2] = y[i];        // 128B-line coalesced
}

extern "C" void kernel_launch(void* const* d_in, const int* in_sizes, int n_in,
                              void* d_out, int out_size, void* d_ws, size_t ws_size,
                              hipStream_t stream) {
    (void)in_sizes; (void)n_in; (void)out_size;
    const float* X   = (const float*)d_in[0];
    const float* ang = (const float*)d_in[1];
    float* out = (float*)d_out;

    bool use_tab = (d_ws != nullptr) && (ws_size >= TAB_BYTES);
    if (use_tab) {
        float2* tab = (float2*)d_ws;
        build_tab_kernel<<<(TAB_ELEMS + 255) / 256, 256, 0, stream>>>(ang, tab);
        butterfly_kernel<true><<<256, 512, 0, stream>>>(X, ang, tab, out);
    } else {
        butterfly_kernel<false><<<256, 512, 0, stream>>>(X, ang, nullptr, out);
    }
}

// Round 15
// 31.599 us; speedup vs baseline: 1.3318x; 1.0020x over previous
//
#include <hip/hip_runtime.h>
#include <math.h>

// OrthogonalButterfly: X (1024 x 8192) fp32, 20 butterfly layers, stride 2^(l%10).
// R14 = 31.7us best: 512thr = 16 f2cols x 32 subs, y=v2f[32], two row maps
// (A/B), 3 transposes / 5 barriers, b128 A-side, pk fp32, LDS 128KB, grid 256.
// R15: same schedule at 256thr = 8 f2cols x 32 subs, LDS 64KB, grid 512 ->
// 2 resident blocks/CU (R14 had 1): block-level pipelining of the entry-load /
// exit-store tails and transpose stalls; 4-wave barrier scope. Row maps,
// swizzle, table, rotations byte-identical to R14.
//
// Row maps (sub in [0,32), i in [0,32)):
//   A: r = sub<<5 | i   layers s=1..16   (SL=1,2,4,8,16)
//   B: r = sub | i<<5   layers s=32..512 (SL=1,2,4,8,16)
// Schedule: load(A) 5L T1 5L(B) T2 5L(A) T3 5L(B) store(B).
// Swizzle xr=(c&7)<<1, elem = c<<10 | (r^xr): b128 8 lanes/slot (floor),
// b64 ~2 lanes/bank (free); bit0 untouched keeps b128 alignment.

#define NROW   1024
#define BATCH  8192
#define BATCH2 (BATCH / 2)
#define DEPTH  20
#define NANG   512
#define TAB_ELEMS (DEPTH * NANG)
#define TAB_BYTES ((size_t)TAB_ELEMS * 8)

typedef float v2f __attribute__((ext_vector_type(2)));

__device__ __host__ __forceinline__ int rowA(int sub, int i){ return (sub << 5) | i; }
__device__ __host__ __forceinline__ int rowB(int sub, int i){ return sub | (i << 5); }

// ---------------- angle table build (identical to R14, verified) ----------------
// slot = 16*sub + p (sub in [0,32), p in [0,16)). Layer l: m10 = l%10,
// SL = 2^(m10%5), phase B iff m10>=5, sp = m10. Pair p -> i0 = 2*(p/SL)*SL
// + p%SL -> r (row map) -> original angle a = ((r>>(sp+1))<<sp) | (r&(2^sp-1)).
__global__ void build_tab_kernel(const float* __restrict__ ang,
                                 float2* __restrict__ tab) {
    int idx = blockIdx.x * blockDim.x + threadIdx.x;
    if (idx >= TAB_ELEMS) return;
    int l = idx >> 9;
    int slot = idx & (NANG - 1);
    int sub = slot >> 4, p = slot & 15;
    int m10 = l % 10;
    int sp = m10;
    int SL = 1 << (m10 % 5);
    int i0 = 2 * (p / SL) * SL + p % SL;
    int r = (m10 >= 5) ? rowB(sub, i0) : rowA(sub, i0);
    int a = ((r >> (sp + 1)) << sp) | (r & ((1 << sp) - 1));
    float th = ang[l * NANG + a];
    float sv, cv;
    sincosf(th, &sv, &cv);
    tab[idx] = make_float2(cv, sv);
}

// ---------------- main kernel ----------------
// Packed rotation (R11-validated): both f2 lanes share (c,s).
__device__ __forceinline__ void rotp(v2f& a, v2f& b, float cv, float sv) {
    v2f c = {cv, cv}, s = {sv, sv};
    v2f x0 = a, x1 = b;
    a = __builtin_elementwise_fma(c, x0, s * x1);
    b = __builtin_elementwise_fma(-s, x0, c * x1);
}

// One layer on 32 v2f rows, local pair-stride SL. Table slice = 8 float4 at
// tf4 + l*256 + 8*sub (16 cos/sin pairs, shared by the 8 c-lanes -> broadcast).
template<int SL>
__device__ __forceinline__ void layer_tab(v2f y[32],
                                          const float4* __restrict__ q4) {
    #pragma unroll
    for (int v = 0; v < 8; ++v) {
        float4 q = q4[v];
        int p0 = 2 * v, p1 = 2 * v + 1;
        int a0 = 2 * (p0 / SL) * SL + p0 % SL;   // constant-folds
        int a1 = 2 * (p1 / SL) * SL + p1 % SL;
        rotp(y[a0], y[a0 + SL], q.x, q.y);
        rotp(y[a1], y[a1 + SL], q.z, q.w);
    }
}

// Fallback without workspace: inline sincos.
template<int SL, bool PB, int SP>
__device__ __forceinline__ void layer_notab(v2f y[32],
                                            const float* __restrict__ angL,
                                            int sub) {
    #pragma unroll
    for (int p = 0; p < 16; ++p) {
        int i0 = 2 * (p / SL) * SL + p % SL;
        int r = PB ? rowB(sub, i0) : rowA(sub, i0);
        int a = ((r >> (SP + 1)) << SP) | (r & ((1 << SP) - 1));
        float th = angL[a];
        float sv, cv;
        __sincosf(th, &sv, &cv);
        rotp(y[i0], y[i0 + SL], cv, sv);
    }
}

template<bool USE_TAB>
__global__ __launch_bounds__(256) void butterfly_kernel(
        const float* __restrict__ X, const float* __restrict__ ang,
        const float2* __restrict__ tab, float* __restrict__ out) {
    __shared__ v2f lds[8 * 1024];        // 64 KB -> 2 resident blocks/CU
    int t = threadIdx.x;
    int c = t & 7;                       // f2-column within block
    int sub = t >> 3;                    // [0,32)
    int bid = blockIdx.x;
    int L = ((bid & 7) << 6) | (bid >> 3);   // XCD-aware, bijective (512 = 8*64)
    int col2 = (L << 3) + c;             // f2-col in [0,4096)
    int xr = (c & 7) << 1;               // swizzle (bit0 clear -> b128 ok)
    v2f* base = lds + (c << 10);

    v2f y[32];
    const v2f* Xp = reinterpret_cast<const v2f*>(X) + col2;
    #pragma unroll
    for (int i = 0; i < 32; ++i)
        y[i] = Xp[rowA(sub, i) * BATCH2];        // 64B-segment coalesced

    const float4* tf4 = reinterpret_cast<const float4*>(tab);
    if (USE_TAB) {
        layer_tab<1 >(y, tf4 + 0 * 256 + 8 * sub);   // s=1
        layer_tab<2 >(y, tf4 + 1 * 256 + 8 * sub);   // s=2
        layer_tab<4 >(y, tf4 + 2 * 256 + 8 * sub);   // s=4
        layer_tab<8 >(y, tf4 + 3 * 256 + 8 * sub);   // s=8
        layer_tab<16>(y, tf4 + 4 * 256 + 8 * sub);   // s=16
    } else {
        layer_notab<1 ,false,0>(y, ang + 0 * NANG, sub);
        layer_notab<2 ,false,1>(y, ang + 1 * NANG, sub);
        layer_notab<4 ,false,2>(y, ang + 2 * NANG, sub);
        layer_notab<8 ,false,3>(y, ang + 3 * NANG, sub);
        layer_notab<16,false,4>(y, ang + 4 * NANG, sub);
    }
    // T1: wr A (b128) / rd B (b64)
    #pragma unroll
    for (int u = 0; u < 16; ++u)
        *reinterpret_cast<float4*>(&base[((sub << 5) + 2 * u) ^ xr]) =
            make_float4(y[2*u].x, y[2*u].y, y[2*u+1].x, y[2*u+1].y);
    __syncthreads();
    #pragma unroll
    for (int i = 0; i < 32; ++i) y[i] = base[rowB(sub, i) ^ xr];

    if (USE_TAB) {
        layer_tab<1 >(y, tf4 + 5 * 256 + 8 * sub);   // s=32
        layer_tab<2 >(y, tf4 + 6 * 256 + 8 * sub);   // s=64
        layer_tab<4 >(y, tf4 + 7 * 256 + 8 * sub);   // s=128
        layer_tab<8 >(y, tf4 + 8 * 256 + 8 * sub);   // s=256
        layer_tab<16>(y, tf4 + 9 * 256 + 8 * sub);   // s=512
    } else {
        layer_notab<1 ,true,5>(y, ang + 5 * NANG, sub);
        layer_notab<2 ,true,6>(y, ang + 6 * NANG, sub);
        layer_notab<4 ,true,7>(y, ang + 7 * NANG, sub);
        layer_notab<8 ,true,8>(y, ang + 8 * NANG, sub);
        layer_notab<16,true,9>(y, ang + 9 * NANG, sub);
    }
    // T2: wr B (b64) / rd A (b128)
    __syncthreads();
    #pragma unroll
    for (int i = 0; i < 32; ++i) base[rowB(sub, i) ^ xr] = y[i];
    __syncthreads();
    #pragma unroll
    for (int u = 0; u < 16; ++u) {
        float4 v = *reinterpret_cast<const float4*>(&base[((sub << 5) + 2 * u) ^ xr]);
        y[2*u].x = v.x; y[2*u].y = v.y; y[2*u+1].x = v.z; y[2*u+1].y = v.w;
    }

    if (USE_TAB) {
        layer_tab<1 >(y, tf4 + 10 * 256 + 8 * sub);  // s=1
        layer_tab<2 >(y, tf4 + 11 * 256 + 8 * sub);  // s=2
        layer_tab<4 >(y, tf4 + 12 * 256 + 8 * sub);  // s=4
        layer_tab<8 >(y, tf4 + 13 * 256 + 8 * sub);  // s=8
        layer_tab<16>(y, tf4 + 14 * 256 + 8 * sub);  // s=16
    } else {
        layer_notab<1 ,false,0>(y, ang + 10 * NANG, sub);
        layer_notab<2 ,false,1>(y, ang + 11 * NANG, sub);
        layer_notab<4 ,false,2>(y, ang + 12 * NANG, sub);
        layer_notab<8 ,false,3>(y, ang + 13 * NANG, sub);
        layer_notab<16,false,4>(y, ang + 14 * NANG, sub);
    }
    // T3: wr A (b128) / rd B (b64)
    __syncthreads();
    #pragma unroll
    for (int u = 0; u < 16; ++u)
        *reinterpret_cast<float4*>(&base[((sub << 5) + 2 * u) ^ xr]) =
            make_float4(y[2*u].x, y[2*u].y, y[2*u+1].x, y[2*u+1].y);
    __syncthreads();
    #pragma unroll
    for (int i = 0; i < 32; ++i) y[i] = base[rowB(sub, i) ^ xr];

    if (USE_TAB) {
        layer_tab<1 >(y, tf4 + 15 * 256 + 8 * sub);  // s=32
        layer_tab<2 >(y, tf4 + 16 * 256 + 8 * sub);  // s=64
        layer_tab<4 >(y, tf4 + 17 * 256 + 8 * sub);  // s=128
        layer_tab<8 >(y, tf4 + 18 * 256 + 8 * sub);  // s=256
        layer_tab<16>(y, tf4 + 19 * 256 + 8 * sub);  // s=512
    } else {
        layer_notab<1 ,true,5>(y, ang + 15 * NANG, sub);
        layer_notab<2 ,true,6>(y, ang + 16 * NANG, sub);
        layer_notab<4 ,true,7>(y, ang + 17 * NANG, sub);
        layer_notab<8 ,true,8>(y, ang + 18 * NANG, sub);
        layer_notab<16,true,9>(y, ang + 19 * NANG, sub);
    }

    v2f* Op = reinterpret_cast<v2f*>(out) + col2;
    #pragma unroll
    for (int i = 0; i < 32; ++i)
        Op[rowB(sub, i) * BATCH2] = y[i];        // 64B-segment coalesced
}

extern "C" void kernel_launch(void* const* d_in, const int* in_sizes, int n_in,
                              void* d_out, int out_size, void* d_ws, size_t ws_size,
                              hipStream_t stream) {
    (void)in_sizes; (void)n_in; (void)out_size;
    const float* X   = (const float*)d_in[0];
    const float* ang = (const float*)d_in[1];
    float* out = (float*)d_out;

    bool use_tab = (d_ws != nullptr) && (ws_size >= TAB_BYTES);
    if (use_tab) {
        float2* tab = (float2*)d_ws;
        build_tab_kernel<<<(TAB_ELEMS + 255) / 256, 256, 0, stream>>>(ang, tab);
        butterfly_kernel<true><<<512, 256, 0, stream>>>(X, ang, tab, out);
    } else {
        butterfly_kernel<false><<<512, 256, 0, stream>>>(X, ang, nullptr, out);
    }
}